// Round 1
// baseline (241.543 us; speedup 1.0000x reference)
//
#include <hip/hip_runtime.h>

#define N_NODES 50000
#define N_EDGES 800000
#define D 128
#define H_BLKS 782     // ceil(800000/1024), 4 edges/thread histogram
#define SC_BLKS 782    // scatter, 4 edges/thread
#define FB_BLKS 12500  // N_NODES*64/256 feature->bf16 convert
#define WT_BLKS 64     // 16384/256 weight transpose->bf16
#define SCAN_BLKS 196  // ceil(50000/256)
#define HIST_PAD 50176 // 196*256 (tail zero-padded so scan needs no guards)

typedef __attribute__((ext_vector_type(8))) short short8;
typedef __attribute__((ext_vector_type(4))) float f32x4;

__device__ __forceinline__ unsigned short f2bf(float f) {
    unsigned u = __float_as_uint(f);
    u += 0x7fff + ((u >> 16) & 1);  // RNE
    return (unsigned short)(u >> 16);
}
__device__ __forceinline__ float lo16f(unsigned u) { return __uint_as_float(u << 16); }
__device__ __forceinline__ float hi16f(unsigned u) { return __uint_as_float(u & 0xffff0000u); }

// ---------------------------------------------------------------------------
// K1 (fused): dst-degree histogram via global atomics (device-filling grid)
// + feature->packed-bf16 fb + W->bf16 n-major Wt. Replaces the 196-block
// bucketing passA: 800k random 4B atomics into a 200KB L2-resident array,
// hidden under the 38MB streaming convert.
// ---------------------------------------------------------------------------
__global__ __launch_bounds__(256) void prep_hist(
    const float2* __restrict__ feat2, unsigned* __restrict__ fb,
    const float* __restrict__ W, unsigned short* __restrict__ Wt,
    const int* __restrict__ edst, int* __restrict__ hist) {
    int blk = blockIdx.x, t = threadIdx.x;
    if (blk < H_BLKS) {
        int e0 = blk * 1024 + t;
#pragma unroll
        for (int j = 0; j < 4; ++j) {
            int e = e0 + j * 256;
            if (e < N_EDGES) atomicAdd(&hist[edst[e]], 1);
        }
        return;
    }
    int b2 = blk - H_BLKS;
    if (b2 < FB_BLKS) {
        int i = b2 * 256 + t;
        float2 f = feat2[i];
        fb[i] = (unsigned)f2bf(f.x) | ((unsigned)f2bf(f.y) << 16);
    } else {
        int idx = (b2 - FB_BLKS) * 256 + t;  // 16384 weight elements
        int n = idx >> 7, k = idx & 127;
        Wt[idx] = f2bf(W[k * 128 + n]);
    }
}

// ---------------------------------------------------------------------------
// K2: single-kernel exclusive scan of the 50000-entry histogram.
// Each block redundantly sums all hist entries before its tile (<=200KB of
// L2-resident reads) -> base, then Hillis-Steele scan of its 256 entries.
// Writes offsets[] (persistent, read by agg_gemm) and cur[] (scatter cursor).
// ---------------------------------------------------------------------------
__global__ __launch_bounds__(256) void scan_all(const int* __restrict__ hist,
                                                int* __restrict__ offsets,
                                                int* __restrict__ cur) {
    __shared__ int ps[256];
    int b = blockIdx.x, t = threadIdx.x;

    int acc = 0;
    for (int i = t; i < b * 256; i += 256) acc += hist[i];
    ps[t] = acc;
    __syncthreads();
    for (int off = 128; off > 0; off >>= 1) {
        if (t < off) ps[t] += ps[t + off];
        __syncthreads();
    }
    int base = ps[0];
    __syncthreads();

    int v = hist[b * 256 + t];  // zero-padded to HIST_PAD, no guard needed
    ps[t] = v;
    __syncthreads();
    for (int off = 1; off < 256; off <<= 1) {
        int x = (t >= off) ? ps[t - off] : 0;
        __syncthreads();
        ps[t] += x;
        __syncthreads();
    }
    int o = base + ps[t] - v;  // exclusive
    int n = b * 256 + t;
    if (n < N_NODES) {
        offsets[n] = o;
        cur[n] = o;
    }
    if (b == SCAN_BLKS - 1 && t == 0) offsets[N_NODES] = N_EDGES;
}

// ---------------------------------------------------------------------------
// K3: scatter edges to their CSR slot. Order within a node is nondeterministic
// (atomic grab) -- fine, aggregation is a float sum. Positions for one node
// cluster (mean degree 16) so the 8B writes mostly merge in L2.
// ---------------------------------------------------------------------------
__global__ __launch_bounds__(256) void scatter(const int* __restrict__ esrc,
                                               const int* __restrict__ edst,
                                               const float* __restrict__ ew,
                                               int* __restrict__ cur,
                                               uint2* __restrict__ sw) {
    int e0 = blockIdx.x * 1024 + threadIdx.x;
#pragma unroll
    for (int j = 0; j < 4; ++j) {
        int e = e0 + j * 256;
        if (e < N_EDGES) {
            int d = edst[e];
            int pos = atomicAdd(&cur[d], 1);
            sw[pos] = make_uint2((unsigned)esrc[e], __float_as_uint(ew[e]));
        }
    }
}

// ---------------------------------------------------------------------------
// K4 (UNCHANGED from previous round, clean A/B): block = 16 nodes, wave
// aggregates 4. 16-edge batches of gathered bf16 rows, software prefetch of
// the next sw batch, then blended rows -> Arows -> 16x128 @ 128x128 MFMA.
// mfma_f32_16x16x32_bf16: A[m=lane&15][k=quad*8+j], B[k][n=lane&15],
// D row=quad*4+reg, col=lane&15 (verified; R2-R7 passed).
// ---------------------------------------------------------------------------
__global__ __launch_bounds__(256, 2) void agg_gemm(const int* __restrict__ offsets,
                                                   const uint2* __restrict__ sw,
                                                   const unsigned* __restrict__ fb,
                                                   const unsigned short* __restrict__ Wt,
                                                   float* __restrict__ out) {
    __shared__ unsigned Arows[16][68];
    int wave = threadIdx.x >> 6;
    int lane = threadIdx.x & 63;
    int row0 = blockIdx.x * 16;

#pragma unroll 1
    for (int i = 0; i < 4; ++i) {
        int n = __builtin_amdgcn_readfirstlane(row0 + wave * 4 + i);
        int b = offsets[n], e2 = offsets[n + 1];
        unsigned us = fb[(size_t)n * 64 + lane];  // self row
        float ax = 0.f, ay = 0.f;
        int e = b;
        int nfull = (e2 - b) >> 4;

        uint2 p[16];
        {   // preload first batch (clamped; OOB-safe: sw is followed by fb in ws)
            int rem = e2 - e;
#pragma unroll
            for (int j = 0; j < 16; ++j) {
                int idx = (j < rem) ? j : (rem > 0 ? rem - 1 : 0);
                p[j] = sw[e + idx];
            }
        }
#pragma unroll 1
        for (int t = 0; t < nfull; ++t) {
            unsigned u[16];
#pragma unroll
            for (int j = 0; j < 16; ++j) u[j] = fb[(size_t)p[j].x * 64 + lane];
            // prefetch next batch while the 16 gathers are in flight
            int en = e + 16;
            int rem = e2 - en;
            uint2 pn[16];
#pragma unroll
            for (int j = 0; j < 16; ++j) {
                int idx = (j < rem) ? j : (rem > 0 ? rem - 1 : 0);
                pn[j] = sw[en + idx];
            }
#pragma unroll
            for (int j = 0; j < 16; ++j) {
                float w = __uint_as_float(p[j].y);
                ax += w * lo16f(u[j]);
                ay += w * hi16f(u[j]);
            }
#pragma unroll
            for (int j = 0; j < 16; ++j) p[j] = pn[j];
            e = en;
        }
        int rem = e2 - e;
        if (rem > 0) {  // tail: p already holds the clamp-padded batch
            unsigned u[16];
#pragma unroll
            for (int j = 0; j < 16; ++j) u[j] = fb[(size_t)p[j].x * 64 + lane];
#pragma unroll
            for (int j = 0; j < 16; ++j) {
                float w = (j < rem) ? __uint_as_float(p[j].y) : 0.f;
                ax += w * lo16f(u[j]);
                ay += w * hi16f(u[j]);
            }
        }
        float rx = 0.5f * (ax + lo16f(us));
        float ry = 0.5f * (ay + hi16f(us));
        Arows[wave * 4 + i][lane] = (unsigned)f2bf(rx) | ((unsigned)f2bf(ry) << 16);
    }
    __syncthreads();

    int quad = lane >> 4;
    int col  = lane & 15;
    short8 a[4];
#pragma unroll
    for (int kk = 0; kk < 4; ++kk)
        a[kk] = *reinterpret_cast<const short8*>(&Arows[col][kk * 16 + quad * 4]);

#pragma unroll
    for (int ii = 0; ii < 2; ++ii) {
        int n0 = wave * 2 + ii;
        const short8* bp = reinterpret_cast<const short8*>(Wt) + ((n0 * 16 + col) * 16 + quad);
        f32x4 acc = {0.f, 0.f, 0.f, 0.f};
        acc = __builtin_amdgcn_mfma_f32_16x16x32_bf16(a[0], bp[0],  acc, 0, 0, 0);
        acc = __builtin_amdgcn_mfma_f32_16x16x32_bf16(a[1], bp[4],  acc, 0, 0, 0);
        acc = __builtin_amdgcn_mfma_f32_16x16x32_bf16(a[2], bp[8],  acc, 0, 0, 0);
        acc = __builtin_amdgcn_mfma_f32_16x16x32_bf16(a[3], bp[12], acc, 0, 0, 0);
#pragma unroll
        for (int rr = 0; rr < 4; ++rr)
            out[(size_t)(row0 + quad * 4 + rr) * D + n0 * 16 + col] = acc[rr];
    }
}

// ---------------------------------------------------------------------------
extern "C" void kernel_launch(void* const* d_in, const int* in_sizes, int n_in,
                              void* d_out, int out_size, void* d_ws, size_t ws_size,
                              hipStream_t stream) {
    const float* feat = (const float*)d_in[0];
    const int*   esrc = (const int*)d_in[1];
    const int*   edst = (const int*)d_in[2];
    const float* ew   = (const float*)d_in[3];
    const float* W    = (const float*)d_in[4];
    float*       out  = (float*)d_out;

    char* ws = (char*)d_ws;
    uint2*          sw      = (uint2*)(ws + 0);                   //  6,400,000
    unsigned*       fb      = (unsigned*)(ws + 6400000);          // 12,800,000
    int*            offsets = (int*)(ws + 19200000);              //    200,004
    unsigned short* Wt      = (unsigned short*)(ws + 19400064);   //     32,768
    // hist/cur alias d_out (dead until agg_gemm overwrites it).
    int* hist = (int*)d_out;                                      //    200,704
    int* cur  = (int*)((char*)d_out + 200704);                    //    200,000

    hipMemsetAsync(hist, 0, HIST_PAD * sizeof(int), stream);
    prep_hist<<<H_BLKS + FB_BLKS + WT_BLKS, 256, 0, stream>>>(
        (const float2*)feat, fb, W, Wt, edst, hist);
    scan_all<<<SCAN_BLKS, 256, 0, stream>>>(hist, offsets, cur);
    scatter<<<SC_BLKS, 256, 0, stream>>>(esrc, edst, ew, cur, sw);
    agg_gemm<<<N_NODES / 16, 256, 0, stream>>>(offsets, sw, fb, Wt, out);
}